// Round 5
// baseline (891.459 us; speedup 1.0000x reference)
//
#include <hip/hip_runtime.h>
#include <stdint.h>

#define DI __device__ __forceinline__

typedef __attribute__((ext_vector_type(4))) float f32x4;
typedef __attribute__((ext_vector_type(8))) unsigned short u16x8;
typedef __attribute__((ext_vector_type(8))) __bf16 bf16x8;

static constexpr int NR = 65536;

// workspace layout (bytes)
static constexpr size_t OFF_WPRED = 0;                              // [128][128] bf16 swz
static constexpr size_t OFF_WBM   = 32768;                          // 8 x [128][128] tiles (K padded 1000->1024)
static constexpr size_t OFF_WFOLD = 294912;                         // 2 x [128][64]
static constexpr size_t OFF_WNODE = 327680;                         // 6 x [128][128] (part{c1,c2,bm} x nhalf)
static constexpr size_t OFF_WM1   = 524288;                         // 6 x [128][64]
static constexpr size_t OFF_WM2   = 622592;                         // [64][128]
static constexpr size_t OFF_BNF   = 638976;                         // 256 f32 folded node bias
static constexpr size_t OFF_C1    = 640000;                         // [N][128] bf16 swz rows
static constexpr size_t OFF_C2    = OFF_C1 + (size_t)NR * 256;
static constexpr size_t OFF_BME   = OFF_C2 + (size_t)NR * 256;

DI unsigned short f2bf(float f) {            // RNE f32->bf16 (finite inputs)
  uint32_t u = __float_as_uint(f);
  u += 0x7fffu + ((u >> 16) & 1u);
  return (unsigned short)(u >> 16);
}

// XOR-16B swizzle inside row-major tile; rowbytes multiple of 128
DI uint32_t swz(uint32_t row, uint32_t cb, uint32_t rowbytes) {
  return row * rowbytes + ((((cb >> 4) ^ (row & 7u)) << 4) | (cb & 15u));
}

using gas_t = const __attribute__((address_space(1))) uint32_t*;
using las_t = __attribute__((address_space(3))) uint32_t*;

DI void gload16(void* lds_dst, const void* gsrc) {   // async global->LDS, 16B/lane
  __builtin_amdgcn_global_load_lds((gas_t)gsrc, (las_t)lds_dst, 16, 0, 0);
}

// MFMA fragment read: row0 + (lane&15) row, cb0 + (lane>>4)*16 col-byte
DI bf16x8 rdfrag(const char* sm, int row0, int cb0, int rowbytes, int l15, int lk) {
  return *(const bf16x8*)(sm + swz((uint32_t)(row0 + l15), (uint32_t)(cb0 + (lk << 4)),
                                   (uint32_t)rowbytes));
}

DI f32x4 mfma16(bf16x8 a, bf16x8 b, f32x4 c) {
  return __builtin_amdgcn_mfma_f32_16x16x32_bf16(a, b, c, 0, 0, 0);
}

DI u16x8 cvt8(f32x4 x0, f32x4 x1) {
  u16x8 pk;
  pk[0] = f2bf(x0[0]); pk[1] = f2bf(x0[1]); pk[2] = f2bf(x0[2]); pk[3] = f2bf(x0[3]);
  pk[4] = f2bf(x1[0]); pk[5] = f2bf(x1[1]); pk[6] = f2bf(x1[2]); pk[7] = f2bf(x1[3]);
  return pk;
}

DI void stw(char* base, int row, int col, int rowbytes, float v) {
  *(unsigned short*)(base + swz((uint32_t)row, (uint32_t)(col * 2), (uint32_t)rowbytes)) = f2bf(v);
}

// ---------------- weight prep: bf16 transpose + swizzle + op-layer fold ----------------
__global__ void prep_kernel(const float* __restrict__ Wpred, const float* __restrict__ Wbm,
                            const float* __restrict__ Wop, const float* __restrict__ Wnode,
                            const float* __restrict__ bop, const float* __restrict__ bnode,
                            const float* __restrict__ Wm1, const float* __restrict__ Wm2,
                            char* __restrict__ ws) {
  const int bid = blockIdx.x, tid = threadIdx.x;
  if (bid == 0) {                                    // W_pred^T [n][k]
    for (int idx = tid; idx < 128 * 128; idx += 256) {
      int n = idx >> 7, k = idx & 127;
      stw(ws + OFF_WPRED, n, k, 256, Wpred[k * 128 + n]);
    }
  } else if (bid <= 8) {                             // W_bm^T k-chunk tiles
    int c = bid - 1;
    char* t = ws + OFF_WBM + (size_t)c * 32768;
    for (int idx = tid; idx < 128 * 128; idx += 256) {
      int n = idx >> 7, kk = idx & 127;
      int gk = c * 128 + kk;
      stw(t, n, kk, 256, gk < 1000 ? Wbm[(size_t)gk * 128 + n] : 0.f);
    }
  } else if (bid <= 10) {                            // Wfold = W_op @ W_node[0:128], ^T halves
    int hf = bid - 9;
    char* t = ws + OFF_WFOLD + (size_t)hf * 16384;
    for (int idx = tid; idx < 128 * 64; idx += 256) {
      int nl = idx >> 6, a = idx & 63;
      int n = hf * 128 + nl;
      float s = 0.f;
      for (int h = 0; h < 128; ++h) s += Wop[a * 128 + h] * Wnode[h * 256 + n];
      stw(t, nl, a, 128, s);
    }
  } else if (bid <= 16) {                            // W_node parts c1,c2,bm ^T n-halves
    int j = bid - 11, p = j >> 1, hf = j & 1;
    char* t = ws + OFF_WNODE + (size_t)j * 32768;
    for (int idx = tid; idx < 128 * 128; idx += 256) {
      int nl = idx >> 7, k = idx & 127;
      stw(t, nl, k, 256, Wnode[(size_t)(128 + p * 128 + k) * 256 + (hf * 128 + nl)]);
    }
  } else if (bid <= 22) {                            // W_m1^T k-tiles [128n][64k]
    int kt = bid - 17;
    char* t = ws + OFF_WM1 + (size_t)kt * 16384;
    for (int idx = tid; idx < 128 * 64; idx += 256) {
      int n = idx >> 6, kk = idx & 63;
      stw(t, n, kk, 128, Wm1[(size_t)(kt * 64 + kk) * 128 + n]);
    }
  } else if (bid == 23) {                            // W_m2^T [64n][128k]
    for (int idx = tid; idx < 64 * 128; idx += 256) {
      int n = idx >> 7, k = idx & 127;
      stw(ws + OFF_WM2, n, k, 256, Wm2[(size_t)k * 64 + n]);
    }
  } else {                                           // folded node bias
    for (int j = tid; j < 256; j += 256) {
      float s = bnode[j];
      for (int h = 0; h < 128; ++h) s += bop[h] * Wnode[h * 256 + j];
      *(float*)(ws + OFF_BNF + (size_t)j * 4) = s;
    }
  }
}

// ---------------- embeddings: cond1/cond2 (min-pooled) + bm_emb -> ws bf16 ----------------
__global__ __launch_bounds__(256, 2)
void embed_kernel(const float* __restrict__ bitmap, const float* __restrict__ has_cond,
                  const float* __restrict__ pred1, const float* __restrict__ pred2,
                  const float* __restrict__ b_pred, const float* __restrict__ b_bm,
                  char* __restrict__ ws) {
  __shared__ __attribute__((aligned(16))) char sm[65536];
  char* R0 = sm;            // 32KB weights
  char* R1 = sm + 32768;    // 32KB acts [128][128] bf16 swz
  const int tid = threadIdx.x, lane = tid & 63, wv = tid >> 6;
  const int l15 = lane & 15, lk = lane >> 4;
  const int g0 = blockIdx.x * 128;
  const int sr = tid >> 1, sh = tid & 1;     // staging: row, half(64 f32)

  float bp[8], bb[8];
#pragma unroll
  for (int nf = 0; nf < 8; ++nf) { bp[nf] = b_pred[nf * 16 + l15]; bb[nf] = b_bm[nf * 16 + l15]; }

  // stage W_pred^T once
#pragma unroll
  for (int i = 0; i < 8; ++i) {
    int seg = wv * 8192 + i * 1024;
    gload16(R0 + seg, ws + OFF_WPRED + seg + lane * 16);
  }

  for (int t = 0; t < 2; ++t) {
    const float* pred = t ? pred2 : pred1;
    char* wdst = ws + (t ? OFF_C2 : OFF_C1);
    float mins[2][8][4];
    for (int p = 0; p < 4; ++p) {
      {  // stage act tile [128 rows][128] f32 -> bf16 swz
        const float* src = pred + ((size_t)(g0 + sr) * 4 + p) * 128 + sh * 64;
#pragma unroll
        for (int u = 0; u < 8; ++u) {
          f32x4 x0 = *(const f32x4*)(src + u * 8);
          f32x4 x1 = *(const f32x4*)(src + u * 8 + 4);
          *(u16x8*)(R1 + sr * 256 + (((sh * 8 + u) ^ (sr & 7)) << 4)) = cvt8(x0, x1);
        }
      }
      __syncthreads();
      f32x4 acc[2][8];
#pragma unroll
      for (int mf = 0; mf < 2; ++mf)
#pragma unroll
        for (int nf = 0; nf < 8; ++nf) acc[mf][nf] = (f32x4)0.f;
#pragma unroll
      for (int ks = 0; ks < 4; ++ks) {
        bf16x8 a0 = rdfrag(R1, 32 * wv, ks * 64, 256, l15, lk);
        bf16x8 a1 = rdfrag(R1, 32 * wv + 16, ks * 64, 256, l15, lk);
#pragma unroll
        for (int nf = 0; nf < 8; ++nf) {
          bf16x8 b = rdfrag(R0, nf * 16, ks * 64, 256, l15, lk);
          acc[0][nf] = mfma16(a0, b, acc[0][nf]);
          acc[1][nf] = mfma16(a1, b, acc[1][nf]);
        }
      }
      __syncthreads();
      if (p == 0) {
#pragma unroll
        for (int mf = 0; mf < 2; ++mf)
#pragma unroll
          for (int nf = 0; nf < 8; ++nf)
#pragma unroll
            for (int r = 0; r < 4; ++r) mins[mf][nf][r] = acc[mf][nf][r];
      } else {
#pragma unroll
        for (int mf = 0; mf < 2; ++mf)
#pragma unroll
          for (int nf = 0; nf < 8; ++nf)
#pragma unroll
            for (int r = 0; r < 4; ++r) mins[mf][nf][r] = fminf(mins[mf][nf][r], acc[mf][nf][r]);
      }
    }
    // bias + store bf16 swz to ws
#pragma unroll
    for (int mf = 0; mf < 2; ++mf)
#pragma unroll
      for (int nf = 0; nf < 8; ++nf)
#pragma unroll
        for (int r = 0; r < 4; ++r) {
          uint32_t grow = g0 + 32 * wv + mf * 16 + lk * 4 + r;
          *(unsigned short*)(wdst + swz(grow, (uint32_t)((nf * 16 + l15) * 2), 256)) =
              f2bf(mins[mf][nf][r] + bp[nf]);
        }
  }

  // ---- bitmap embedding: K loop over 8 chunks of 128 ----
  f32x4 acc[2][8];
#pragma unroll
  for (int mf = 0; mf < 2; ++mf)
#pragma unroll
    for (int nf = 0; nf < 8; ++nf) acc[mf][nf] = (f32x4)0.f;

  for (int c = 0; c < 8; ++c) {
#pragma unroll
    for (int i = 0; i < 8; ++i) {   // stage W_bm chunk
      int seg = wv * 8192 + i * 1024;
      gload16(R0 + seg, ws + OFF_WBM + (size_t)c * 32768 + seg + lane * 16);
    }
    {   // stage bitmap chunk (pad K 1000->1024 with zeros)
      const float* src = bitmap + (size_t)(g0 + sr) * 1000 + c * 128 + sh * 64;
      const int vu = (c < 7 || sh == 0) ? 8 : 5;     // 1000 = 896+64+40, 40=5 units
#pragma unroll
      for (int u = 0; u < 8; ++u) {
        u16x8 pk;
        if (u < vu) {
          f32x4 x0 = *(const f32x4*)(src + u * 8);
          f32x4 x1 = *(const f32x4*)(src + u * 8 + 4);
          pk = cvt8(x0, x1);
        } else {
          pk = (u16x8)(unsigned short)0;
        }
        *(u16x8*)(R1 + sr * 256 + (((sh * 8 + u) ^ (sr & 7)) << 4)) = pk;
      }
    }
    __syncthreads();
#pragma unroll
    for (int ks = 0; ks < 4; ++ks) {
      bf16x8 a0 = rdfrag(R1, 32 * wv, ks * 64, 256, l15, lk);
      bf16x8 a1 = rdfrag(R1, 32 * wv + 16, ks * 64, 256, l15, lk);
#pragma unroll
      for (int nf = 0; nf < 8; ++nf) {
        bf16x8 b = rdfrag(R0, nf * 16, ks * 64, 256, l15, lk);
        acc[0][nf] = mfma16(a0, b, acc[0][nf]);
        acc[1][nf] = mfma16(a1, b, acc[1][nf]);
      }
    }
    __syncthreads();
  }
  float hcv[2][4];
#pragma unroll
  for (int mf = 0; mf < 2; ++mf)
#pragma unroll
    for (int r = 0; r < 4; ++r)
      hcv[mf][r] = has_cond[g0 + 32 * wv + mf * 16 + lk * 4 + r];
#pragma unroll
  for (int mf = 0; mf < 2; ++mf)
#pragma unroll
    for (int nf = 0; nf < 8; ++nf)
#pragma unroll
      for (int r = 0; r < 4; ++r) {
        uint32_t grow = g0 + 32 * wv + mf * 16 + lk * 4 + r;
        float v = (acc[mf][nf][r] + bb[nf]) * hcv[mf][r];
        *(unsigned short*)(ws + OFF_BME + swz(grow, (uint32_t)((nf * 16 + l15) * 2), 256)) = f2bf(v);
      }
}

// ---------------- final: node + cc + m1 + m2 + heads ----------------
__global__ __launch_bounds__(256, 2)
void final_kernel(const float* __restrict__ op_vec, const float* __restrict__ extra,
                  const float* __restrict__ left_cc, const float* __restrict__ right_cc,
                  const float* __restrict__ W_cc, const float* __restrict__ b_cc,
                  const float* __restrict__ b_m1, const float* __restrict__ b_m2,
                  const float* __restrict__ W_c1, const float* __restrict__ b_c1,
                  const float* __restrict__ W_c2, const float* __restrict__ b_c2,
                  const float* __restrict__ W_k1, const float* __restrict__ b_k1,
                  const float* __restrict__ W_k2, const float* __restrict__ b_k2,
                  const char* __restrict__ ws, float* __restrict__ out) {
  __shared__ __attribute__((aligned(16))) char sm[65536];
  char* R0 = sm;           // 32KB: node W tiles -> ne[64][256]bf16 -> m2out f32 + hc f32
  char* R1 = sm + 32768;   // 16KB: A staging -> m1/m2 W tiles
  char* R2 = sm + 49152;   // 16KB: cc tile -> m tile
  const int tid = threadIdx.x, lane = tid & 63, wv = tid >> 6;
  const int l15 = lane & 15, lk = lane >> 4;
  const int g0 = blockIdx.x * 64;

  f32x4 accn[2][8];
#pragma unroll
  for (int hf = 0; hf < 2; ++hf)
#pragma unroll
    for (int nf = 0; nf < 8; ++nf) accn[hf][nf] = (f32x4)0.f;

  {   // stage opx = [op_vec|extra] tile [64][64] bf16 swz (rowbytes 128)
    int r = tid >> 2, q = tid & 3;
    const float* s0 = op_vec + (size_t)(g0 + r) * 32 + q * 8;
    const float* s1 = extra + (size_t)(g0 + r) * 32 + q * 8;
    f32x4 a0 = *(const f32x4*)s0, a1 = *(const f32x4*)(s0 + 4);
    f32x4 e0 = *(const f32x4*)s1, e1 = *(const f32x4*)(s1 + 4);
    *(u16x8*)(R1 + r * 128 + ((q ^ (r & 7)) << 4)) = cvt8(a0, a1);
    *(u16x8*)(R1 + r * 128 + (((q + 4) ^ (r & 7)) << 4)) = cvt8(e0, e1);
  }
  for (int part = 0; part < 4; ++part) {
    if (part > 0) {   // stage cond/bm tile 16KB
      size_t so = (part == 1 ? OFF_C1 : part == 2 ? OFF_C2 : OFF_BME) + (size_t)g0 * 256;
#pragma unroll
      for (int i = 0; i < 4; ++i) {
        int seg = wv * 4096 + i * 1024;
        gload16(R1 + seg, ws + so + seg + lane * 16);
      }
    }
    const int nks = part ? 4 : 2;
    const int rb = part ? 256 : 128;
#pragma unroll
    for (int hf = 0; hf < 2; ++hf) {
      if (part == 0) {
#pragma unroll
        for (int i = 0; i < 4; ++i) {
          int seg = wv * 4096 + i * 1024;
          gload16(R0 + seg, ws + OFF_WFOLD + (size_t)hf * 16384 + seg + lane * 16);
        }
      } else {
#pragma unroll
        for (int i = 0; i < 8; ++i) {
          int seg = wv * 8192 + i * 1024;
          gload16(R0 + seg, ws + OFF_WNODE + (size_t)((part - 1) * 2 + hf) * 32768 + seg + lane * 16);
        }
      }
      __syncthreads();
      for (int ks = 0; ks < nks; ++ks) {
        bf16x8 a = rdfrag(R1, 16 * wv, ks * 64, rb, l15, lk);
#pragma unroll
        for (int nf = 0; nf < 8; ++nf) {
          bf16x8 b = rdfrag(R0, nf * 16, ks * 64, rb, l15, lk);
          accn[hf][nf] = mfma16(a, b, accn[hf][nf]);
        }
      }
      __syncthreads();
    }
  }
  // node epilogue: bias + relu -> ne [64][256] bf16 swz @ R0 (rowbytes 512)
#pragma unroll
  for (int hf = 0; hf < 2; ++hf)
#pragma unroll
    for (int nf = 0; nf < 8; ++nf) {
      float bn = *(const float*)(ws + OFF_BNF + (size_t)(hf * 128 + nf * 16 + l15) * 4);
#pragma unroll
      for (int r = 0; r < 4; ++r) {
        float v = fmaxf(0.f, accn[hf][nf][r] + bn);
        uint32_t lr = 16 * wv + lk * 4 + r;
        *(unsigned short*)(R0 + swz(lr, (uint32_t)((hf * 128 + nf * 16 + l15) * 2), 512)) = f2bf(v);
      }
    }
  {   // cc embeddings (VALU, K=2) -> R2 [64][128] bf16 swz (rowbytes 256)
    int r = tid >> 2, q = tid & 3, sd = q >> 1, jg = q & 1;
    const float* cc = sd ? right_cc : left_cc;
    float x0 = cc[(size_t)(g0 + r) * 2], x1 = cc[(size_t)(g0 + r) * 2 + 1];
#pragma unroll
    for (int u = 0; u < 4; ++u) {
      u16x8 pk;
#pragma unroll
      for (int j = 0; j < 8; ++j) {
        int jj = jg * 32 + u * 8 + j;
        pk[j] = f2bf(fmaxf(0.f, x0 * W_cc[jj] + x1 * W_cc[64 + jj] + b_cc[jj]));
      }
      int unit = sd * 8 + jg * 4 + u;
      *(u16x8*)(R2 + r * 256 + ((unit ^ (r & 7)) << 4)) = pk;
    }
  }
  // m1: K = 256(ne) + 128(cc), W tiles [128][64] staged in R1
  f32x4 acc1[8];
#pragma unroll
  for (int nf = 0; nf < 8; ++nf) acc1[nf] = (f32x4)0.f;
#pragma unroll
  for (int i = 0; i < 4; ++i) {
    int seg = wv * 4096 + i * 1024;
    gload16(R1 + seg, ws + OFF_WM1 + seg + lane * 16);
  }
  __syncthreads();
  for (int kt = 0; kt < 6; ++kt) {
    const char* Ab = (kt < 4) ? R0 : R2;
    int cb0 = (kt < 4) ? kt * 128 : (kt - 4) * 128;
    int rb = (kt < 4) ? 512 : 256;
#pragma unroll
    for (int ks = 0; ks < 2; ++ks) {
      bf16x8 a = rdfrag(Ab, 16 * wv, cb0 + ks * 64, rb, l15, lk);
#pragma unroll
      for (int nf = 0; nf < 8; ++nf) {
        bf16x8 b = rdfrag(R1, nf * 16, ks * 64, 128, l15, lk);
        acc1[nf] = mfma16(a, b, acc1[nf]);
      }
    }
    __syncthreads();
    if (kt < 5) {
#pragma unroll
      for (int i = 0; i < 4; ++i) {
        int seg = wv * 4096 + i * 1024;
        gload16(R1 + seg, ws + OFF_WM1 + (size_t)(kt + 1) * 16384 + seg + lane * 16);
      }
      __syncthreads();
    }
  }
  // m1 epilogue -> m [64][128] bf16 swz @ R2
#pragma unroll
  for (int nf = 0; nf < 8; ++nf) {
    float b1 = b_m1[nf * 16 + l15];
#pragma unroll
    for (int r = 0; r < 4; ++r) {
      float v = fmaxf(0.f, acc1[nf][r] + b1);
      uint32_t lr = 16 * wv + lk * 4 + r;
      *(unsigned short*)(R2 + swz(lr, (uint32_t)((nf * 16 + l15) * 2), 256)) = f2bf(v);
    }
  }
#pragma unroll
  for (int i = 0; i < 4; ++i) {   // stage W_m2
    int seg = wv * 4096 + i * 1024;
    gload16(R1 + seg, ws + OFF_WM2 + seg + lane * 16);
  }
  __syncthreads();
  f32x4 acc2[4];
#pragma unroll
  for (int nf = 0; nf < 4; ++nf) acc2[nf] = (f32x4)0.f;
#pragma unroll
  for (int ks = 0; ks < 4; ++ks) {
    bf16x8 a = rdfrag(R2, 16 * wv, ks * 64, 256, l15, lk);
#pragma unroll
    for (int nf = 0; nf < 4; ++nf) {
      bf16x8 b = rdfrag(R1, nf * 16, ks * 64, 256, l15, lk);
      acc2[nf] = mfma16(a, b, acc2[nf]);
    }
  }
  // m2out f32 [64][64] plain @ R0[0:16K]
#pragma unroll
  for (int nf = 0; nf < 4; ++nf) {
    float b2 = b_m2[nf * 16 + l15];
#pragma unroll
    for (int r = 0; r < 4; ++r) {
      float v = fmaxf(0.f, acc2[nf][r] + b2);
      uint32_t lr = 16 * wv + lk * 4 + r;
      *(float*)(R0 + lr * 256 + (size_t)(nf * 16 + l15) * 4) = v;
    }
  }
  __syncthreads();
  {   // heads hidden: 4 threads per row
    int r = tid >> 2, q = tid & 3;
    const float* mrow = (const float*)(R0 + r * 256);
    float ac[8], ak[8];
#pragma unroll
    for (int j = 0; j < 8; ++j) { ac[j] = b_c1[q * 8 + j]; ak[j] = b_k1[q * 8 + j]; }
    for (int k = 0; k < 64; ++k) {
      float mv = mrow[k];
      const float* wc = W_c1 + k * 32 + q * 8;
      const float* wk = W_k1 + k * 32 + q * 8;
#pragma unroll
      for (int j = 0; j < 8; ++j) { ac[j] += mv * wc[j]; ak[j] += mv * wk[j]; }
    }
    float* hc = (float*)(R0 + 16384 + r * 256);
#pragma unroll
    for (int j = 0; j < 8; ++j) {
      hc[q * 8 + j] = fmaxf(0.f, ac[j]);
      hc[32 + q * 8 + j] = fmaxf(0.f, ak[j]);
    }
  }
  __syncthreads();
  if (tid < 128) {
    int r = tid >> 1, hd = tid & 1;
    const float* hc = (const float*)(R0 + 16384 + r * 256);
    const float* w2 = hd ? W_k2 : W_c2;
    float s = hd ? b_k2[0] : b_c2[0];
#pragma unroll
    for (int j = 0; j < 32; ++j) s += hc[hd * 32 + j] * w2[j];
    out[(size_t)(g0 + r) * 2 + hd] = 1.f / (1.f + __expf(-s));
  }
}

extern "C" void kernel_launch(void* const* d_in, const int* in_sizes, int n_in,
                              void* d_out, int out_size, void* d_ws, size_t ws_size,
                              hipStream_t stream) {
  (void)in_sizes; (void)n_in; (void)out_size; (void)ws_size;
  const float* op_vec   = (const float*)d_in[0];
  const float* extra    = (const float*)d_in[1];
  const float* bitmap   = (const float*)d_in[2];
  const float* has_cond = (const float*)d_in[3];
  const float* pred1    = (const float*)d_in[4];
  const float* pred2    = (const float*)d_in[5];
  const float* left_cc  = (const float*)d_in[6];
  const float* right_cc = (const float*)d_in[7];
  const float* W_op   = (const float*)d_in[8];
  const float* b_op   = (const float*)d_in[9];
  const float* W_pred = (const float*)d_in[10];
  const float* b_pred = (const float*)d_in[11];
  const float* W_bm   = (const float*)d_in[12];
  const float* b_bm   = (const float*)d_in[13];
  const float* W_cc   = (const float*)d_in[14];
  const float* b_cc   = (const float*)d_in[15];
  const float* W_node = (const float*)d_in[16];
  const float* b_node = (const float*)d_in[17];
  const float* W_m1   = (const float*)d_in[18];
  const float* b_m1   = (const float*)d_in[19];
  const float* W_m2   = (const float*)d_in[20];
  const float* b_m2   = (const float*)d_in[21];
  const float* W_c1   = (const float*)d_in[22];
  const float* b_c1   = (const float*)d_in[23];
  const float* W_c2   = (const float*)d_in[24];
  const float* b_c2   = (const float*)d_in[25];
  const float* W_k1   = (const float*)d_in[26];
  const float* b_k1   = (const float*)d_in[27];
  const float* W_k2   = (const float*)d_in[28];
  const float* b_k2   = (const float*)d_in[29];
  char* ws = (char*)d_ws;
  float* out = (float*)d_out;

  prep_kernel<<<25, 256, 0, stream>>>(W_pred, W_bm, W_op, W_node, b_op, b_node, W_m1, W_m2, ws);
  embed_kernel<<<512, 256, 0, stream>>>(bitmap, has_cond, pred1, pred2, b_pred, b_bm, ws);
  final_kernel<<<1024, 256, 0, stream>>>(op_vec, extra, left_cc, right_cc, W_cc, b_cc,
                                         b_m1, b_m2, W_c1, b_c1, W_c2, b_c2,
                                         W_k1, b_k1, W_k2, b_k2, ws, out);
}